// Round 6
// baseline (718.164 us; speedup 1.0000x reference)
//
#include <hip/hip_runtime.h>

#define DIM    20
#define NN     200000
#define EE     6400000
#define ITERS  3
#define BLOCK  256

// Bucketing geometry: fine bucket = 64 nodes
#define NODES_PER_FINE   64
#define NFINE            3125        // 200000/64 exactly
#define NCOARSE          98          // ceil(200000/2048)
#define FINE_PER_COARSE  32
#define TILE             4096        // edges per block tile
#define IPT              16          // items per thread (TILE/BLOCK)

typedef unsigned int u32;

// ---------------- K1: fine-bucket histogram (LDS-binned) ----------------
__global__ __launch_bounds__(BLOCK) void k1_count(const int* __restrict__ edst,
                                                  int* __restrict__ fine_cnt) {
    __shared__ u32 lhist[NFINE];
    int tid = threadIdx.x;
    for (int i = tid; i < NFINE; i += BLOCK) lhist[i] = 0;
    __syncthreads();
    for (int e = blockIdx.x * BLOCK + tid; e < EE; e += gridDim.x * BLOCK) {
        int d = edst[e];
        atomicAdd(&lhist[d >> 6], 1u);
    }
    __syncthreads();
    for (int i = tid; i < NFINE; i += BLOCK) {
        u32 v = lhist[i];
        if (v) atomicAdd((u32*)&fine_cnt[i], v);
    }
}

// ---------------- K2: scan fine counts -> bases/cursors ----------------
__global__ __launch_bounds__(BLOCK) void k2_scan(const int* __restrict__ fine_cnt,
                                                 int* __restrict__ fine_base,
                                                 int* __restrict__ fine_cursor,
                                                 int* __restrict__ coarse_base,
                                                 int* __restrict__ coarse_cursor) {
    const int CH = 13;                       // 256*13 = 3328 >= 3125
    int tid = threadIdx.x;
    int loc[CH];
    int base = tid * CH;
    int s = 0;
    #pragma unroll
    for (int j = 0; j < CH; ++j) {
        int idx = base + j;
        int v = (idx < NFINE) ? fine_cnt[idx] : 0;
        loc[j] = v; s += v;
    }
    __shared__ int wsum[4];
    int lane = tid & 63, wid = tid >> 6;
    int incl = s;
    #pragma unroll
    for (int off = 1; off < 64; off <<= 1) {
        int t = __shfl_up(incl, off, 64);
        if (lane >= off) incl += t;
    }
    if (lane == 63) wsum[wid] = incl;
    __syncthreads();
    int woff = 0;
    for (int w = 0; w < wid; ++w) woff += wsum[w];
    int run = woff + incl - s;
    #pragma unroll
    for (int j = 0; j < CH; ++j) {
        int idx = base + j;
        if (idx < NFINE) {
            fine_base[idx]   = run;
            fine_cursor[idx] = run;
            run += loc[j];
        }
    }
    if (tid == 0) fine_base[NFINE] = EE;
    __syncthreads();
    if (tid < NCOARSE + 1) {
        int f = tid * FINE_PER_COARSE; if (f > NFINE) f = NFINE;
        int v = fine_base[f];
        coarse_base[tid] = v;
        if (tid < NCOARSE) coarse_cursor[tid] = v;
    }
}

// ---------------- P1: split edges into 98 coarse buckets ----------------
// item u32 = dlow(11) | src<<11 (18) | dep<<29 (3)
__global__ __launch_bounds__(BLOCK) void p1_split(const int* __restrict__ esrc,
                                                  const int* __restrict__ edst,
                                                  const int* __restrict__ depth,
                                                  int* __restrict__ coarse_cursor,
                                                  u32* __restrict__ buf1) {
    __shared__ u32 lhist[NCOARSE];
    __shared__ u32 gbase[NCOARSE];
    int tid = threadIdx.x;
    int start = blockIdx.x * TILE;
    if (tid < NCOARSE) lhist[tid] = 0;
    __syncthreads();

    u32 item[IPT]; u32 key[IPT]; u32 rank[IPT];
    #pragma unroll
    for (int k = 0; k < IPT; ++k) {
        int e = start + k * BLOCK + tid;
        if (e < EE) {
            int d = edst[e];
            int s = esrc[e];
            u32 dep = (u32)depth[s];
            u32 c = (u32)d >> 11;
            key[k]  = c;
            item[k] = ((u32)d & 2047u) | ((u32)s << 11) | (dep << 29);
            rank[k] = atomicAdd(&lhist[c], 1u);
        }
    }
    __syncthreads();
    if (tid < NCOARSE) {
        u32 cnt = lhist[tid];
        gbase[tid] = cnt ? (u32)atomicAdd((u32*)&coarse_cursor[tid], cnt) : 0u;
    }
    __syncthreads();
    #pragma unroll
    for (int k = 0; k < IPT; ++k) {
        int e = start + k * BLOCK + tid;
        if (e < EE) buf1[gbase[key[k]] + rank[k]] = item[k];
    }
}

// ---------------- P2: coarse -> fine (64-node) buckets ----------------
// item u32 = ln(6) | src<<6 (18) | dep<<24 (3)
__global__ __launch_bounds__(BLOCK) void p2_split(const u32* __restrict__ buf1,
                                                  const int* __restrict__ coarse_base,
                                                  int* __restrict__ fine_cursor,
                                                  u32* __restrict__ buf2) {
    __shared__ u32 lhist[2 * FINE_PER_COARSE];
    __shared__ u32 gbase[2 * FINE_PER_COARSE];
    __shared__ int cb[NCOARSE + 1];
    __shared__ int sc0;
    int tid = threadIdx.x;
    int start = blockIdx.x * TILE;
    if (tid < NCOARSE + 1) cb[tid] = coarse_base[tid];
    if (tid < 2 * FINE_PER_COARSE) { lhist[tid] = 0; gbase[tid] = 0; }
    __syncthreads();
    if (tid == 0) {
        int c = 0;
        while (c + 1 < NCOARSE && cb[c + 1] <= start) ++c;
        sc0 = c;
    }
    __syncthreads();
    int c0 = sc0;
    int b1 = cb[c0 + 1];

    u32 item[IPT]; u32 key[IPT]; u32 rank[IPT];
    #pragma unroll
    for (int k = 0; k < IPT; ++k) {
        int i = start + k * BLOCK + tid;
        if (i < EE) {
            u32 w = buf1[i];
            u32 dlow = w & 2047u;
            u32 sdep = w >> 11;               // src(18) | dep<<18
            u32 kk = ((i < b1) ? 0u : (u32)FINE_PER_COARSE) + (dlow >> 6);
            key[k]  = kk;
            item[k] = (dlow & 63u) | (sdep << 6);
            rank[k] = atomicAdd(&lhist[kk], 1u);
        }
    }
    __syncthreads();
    if (tid < 2 * FINE_PER_COARSE) {
        u32 cnt = lhist[tid];
        int idx = c0 * FINE_PER_COARSE + tid;
        if (cnt && idx < NFINE)
            gbase[tid] = (u32)atomicAdd((u32*)&fine_cursor[idx], cnt);
    }
    __syncthreads();
    #pragma unroll
    for (int k = 0; k < IPT; ++k) {
        int i = start + k * BLOCK + tid;
        if (i < EE) buf2[gbase[key[k]] + rank[k]] = item[k];
    }
}

// ---------------- PB: sort each fine bucket by (node, depth) ----------------
// emits node-ordered, depth-sorted ssrc (plain src index) + ptr + packed
// per-depth prefix counts cnt3[u] = c_le1 | c_le2<<10 | c_le3<<20
__global__ __launch_bounds__(BLOCK) void pb_sort(const u32* __restrict__ buf2,
                                                 const int* __restrict__ fine_base,
                                                 int* __restrict__ ptr,
                                                 u32* __restrict__ cnt3,
                                                 u32* __restrict__ ssrc) {
    __shared__ u32 hist[512];
    __shared__ u32 ebase[512];
    __shared__ u32 lout[TILE];
    __shared__ u32 wsum[4];
    int tid = threadIdx.x;
    int b = blockIdx.x;
    int lo = fine_base[b];
    int hi = fine_base[b + 1];
    int cnt = hi - lo;
    hist[tid] = 0; hist[tid + 256] = 0;
    __syncthreads();

    u32 item[IPT]; u32 key[IPT]; u32 rank[IPT];
    #pragma unroll
    for (int k = 0; k < IPT; ++k) {
        int i = lo + k * BLOCK + tid;
        if (i < hi) {
            u32 w = buf2[i];
            u32 kk = (w & 63u) * 8u + (w >> 24);     // ln*8 + dep
            key[k]  = kk;
            item[k] = (w >> 6) & 0x3FFFFu;           // src
            rank[k] = atomicAdd(&hist[kk], 1u);
        }
    }
    __syncthreads();
    {
        u32 s0 = hist[2 * tid], s1 = hist[2 * tid + 1];
        u32 s = s0 + s1;
        int lane = tid & 63, wid = tid >> 6;
        u32 incl = s;
        #pragma unroll
        for (int off = 1; off < 64; off <<= 1) {
            u32 t = __shfl_up((int)incl, off, 64);
            if (lane >= off) incl += t;
        }
        if (lane == 63) wsum[wid] = incl;
        __syncthreads();
        u32 woff = 0;
        for (int w = 0; w < wid; ++w) woff += wsum[w];
        u32 excl = woff + incl - s;
        ebase[2 * tid]     = excl;
        ebase[2 * tid + 1] = excl + s0;
    }
    __syncthreads();
    if (tid < NODES_PER_FINE) {
        u32 base0 = ebase[tid * 8];
        u32 c1 = ebase[tid * 8 + 2] - base0;
        u32 c2 = ebase[tid * 8 + 3] - base0;
        u32 c3 = ebase[tid * 8 + 4] - base0;
        int u = b * NODES_PER_FINE + tid;
        ptr[u]  = lo + (int)base0;
        cnt3[u] = c1 | (c2 << 10) | (c3 << 20);
    }
    #pragma unroll
    for (int k = 0; k < IPT; ++k) {
        int i = lo + k * BLOCK + tid;
        if (i < hi) lout[ebase[key[k]] + rank[k]] = item[k];
    }
    __syncthreads();
    for (int j = tid; j < cnt; j += BLOCK) ssrc[lo + j] = lout[j];
}

// ---------------- hconv: fp32 h -> bf16 rows padded to 64 B ----------------
__device__ __forceinline__ u32 pack_bf16x2(float a, float b) {
    u32 ua = __float_as_uint(a);
    u32 ub = __float_as_uint(b);
    ua = (ua + 0x7FFFu + ((ua >> 16) & 1u)) >> 16;
    ub = (ub + 0x7FFFu + ((ub >> 16) & 1u)) & 0xFFFF0000u;
    return ua | ub;
}

__global__ __launch_bounds__(BLOCK) void hconv(const float* __restrict__ h,
                                               u32* __restrict__ hb) {
    int g = blockIdx.x * BLOCK + threadIdx.x;
    if (g >= NN * 16) return;
    int node = g >> 4, slot = g & 15;
    u32 v = 0;
    if (slot < 10) {
        float2 f = *(const float2*)(h + (size_t)node * DIM + slot * 2);
        v = pack_bf16x2(f.x, f.y);
    }
    hb[g] = v;
}

// ---------------- gather: 4-lane teams, register accumulate ----------------

__device__ __forceinline__ float bl(u32 w) { return __uint_as_float(w << 16); }
__device__ __forceinline__ float bh(u32 w) { return __uint_as_float(w & 0xFFFF0000u); }

__device__ __forceinline__ void acc_bf16row(float* x, uint4 A, uint4 B, uint2 C) {
    x[0]+=bl(A.x);  x[1]+=bh(A.x);  x[2]+=bl(A.y);  x[3]+=bh(A.y);
    x[4]+=bl(A.z);  x[5]+=bh(A.z);  x[6]+=bl(A.w);  x[7]+=bh(A.w);
    x[8]+=bl(B.x);  x[9]+=bh(B.x);  x[10]+=bl(B.y); x[11]+=bh(B.y);
    x[12]+=bl(B.z); x[13]+=bh(B.z); x[14]+=bl(B.w); x[15]+=bh(B.w);
    x[16]+=bl(C.x); x[17]+=bh(C.x); x[18]+=bl(C.y); x[19]+=bh(C.y);
}

__global__ __launch_bounds__(BLOCK) void gather4(
    const u32* __restrict__ hb_in, const int* __restrict__ depth,
    const int* __restrict__ ptr, const u32* __restrict__ cnt3,
    const u32* __restrict__ ssrc, float* __restrict__ xbuf,
    int it, int shift)
{
    int gid = blockIdx.x * BLOCK + threadIdx.x;
    int u = gid >> 2;                 // node
    int t = threadIdx.x & 3;          // team lane
    if (u >= NN) return;
    int lim = ITERS - it;
    if (depth[u] > lim) return;       // inactive dst: x never read

    int p = ptr[u];
    int d = (int)((cnt3[u] >> shift) & 1023u);

    float x[DIM];
    #pragma unroll
    for (int k = 0; k < DIM; ++k) x[k] = 0.0f;

    int e = t;
    for (; e + 4 < d; e += 8) {       // 2 edges in flight per lane
        u32 v0 = ssrc[p + e];
        u32 v1 = ssrc[p + e + 4];
        const u32* r0 = hb_in + (size_t)v0 * 16;
        const u32* r1 = hb_in + (size_t)v1 * 16;
        uint4 A0 = *(const uint4*)r0; uint4 B0 = *(const uint4*)(r0 + 4);
        uint2 C0 = *(const uint2*)(r0 + 8);
        uint4 A1 = *(const uint4*)r1; uint4 B1 = *(const uint4*)(r1 + 4);
        uint2 C1 = *(const uint2*)(r1 + 8);
        acc_bf16row(x, A0, B0, C0);
        acc_bf16row(x, A1, B1, C1);
    }
    if (e < d) {
        u32 v0 = ssrc[p + e];
        const u32* r0 = hb_in + (size_t)v0 * 16;
        uint4 A0 = *(const uint4*)r0; uint4 B0 = *(const uint4*)(r0 + 4);
        uint2 C0 = *(const uint2*)(r0 + 8);
        acc_bf16row(x, A0, B0, C0);
    }

    // team butterfly reduce: all 4 lanes end with full x
    #pragma unroll
    for (int k = 0; k < DIM; ++k) {
        x[k] += __shfl_xor(x[k], 1, 64);
        x[k] += __shfl_xor(x[k], 2, 64);
    }

    // coalesced team store: lane t writes dwords t, 4+t, ..., 16+t
    float* xr = xbuf + (size_t)u * DIM;
    #pragma unroll
    for (int q = 0; q < 5; ++q) xr[q * 4 + t] = x[q * 4 + t];
}

// ---------------- GRU node update: 4 threads per node ----------------

__device__ __forceinline__ float fast_sigmoid(float t) {
    return 1.0f / (1.0f + __expf(-t));
}
__device__ __forceinline__ float fast_tanh(float t) {
    t = fminf(fmaxf(t, -15.0f), 15.0f);
    float e2 = __expf(2.0f * t);
    return (e2 - 1.0f) / (e2 + 1.0f);
}

// 4 threads/node, thread t computes output rows j0..j0+4 (j0 = t*5).
// Phase A: x-partials for Wz/Wr/Wh; phase B: h-partials for Uz/Ur + gates;
// phase C: rh team-exchange + Uh matvec; epilogue via LDS for coalesced stores.
__global__ __launch_bounds__(BLOCK, 6) void gru_node4(
    const float* __restrict__ h_in, float* __restrict__ h_out,
    u32* __restrict__ hb_out,
    const int* __restrict__ depth, const float* __restrict__ xbuf,
    const float* __restrict__ Wz, const float* __restrict__ bWz,
    const float* __restrict__ Uz, const float* __restrict__ bUz,
    const float* __restrict__ Wr, const float* __restrict__ bWr,
    const float* __restrict__ Ur, const float* __restrict__ bUr,
    const float* __restrict__ Wh, const float* __restrict__ bWh,
    const float* __restrict__ Uh, const float* __restrict__ bUh,
    int it, int isFinal)
{
    __shared__ float xl[64 * DIM];
    int tid = threadIdx.x;
    int nl  = tid >> 2;               // node within block (0..63)
    int t   = tid & 3;                // team lane
    int j0  = t * 5;
    int u   = blockIdx.x * 64 + nl;   // NN = 3125*64 exactly, no tail
    int lim = ITERS - it;
    bool act = depth[u] <= lim;

    if (act) {
        float az[5], ar[5], ah[5];
        #pragma unroll
        for (int jj = 0; jj < 5; ++jj) {
            az[jj] = bWz[j0 + jj] + bUz[j0 + jj];
            ar[jj] = bWr[j0 + jj] + bUr[j0 + jj];
            ah[jj] = bWh[j0 + jj] + bUh[j0 + jj];
        }

        // ---- phase A: x-dependent partials (x live, then dropped) ----
        {
            float x[DIM];
            const float4* xv = (const float4*)(xbuf + (size_t)u * DIM);
            #pragma unroll
            for (int q = 0; q < 5; ++q) {
                float4 v = xv[q];
                x[q*4] = v.x; x[q*4+1] = v.y; x[q*4+2] = v.z; x[q*4+3] = v.w;
            }
            #pragma unroll
            for (int jj = 0; jj < 5; ++jj) {
                const float* wz = Wz + (size_t)(j0 + jj) * DIM;
                const float* wr = Wr + (size_t)(j0 + jj) * DIM;
                const float* wh = Wh + (size_t)(j0 + jj) * DIM;
                #pragma unroll
                for (int k = 0; k < DIM; ++k) {
                    az[jj] += x[k] * wz[k];
                    ar[jj] += x[k] * wr[k];
                    ah[jj] += x[k] * wh[k];
                }
            }
        }

        // ---- phase B: h-dependent partials + gates ----
        float zz[5], rh[5], hmine[5];
        {
            float h[DIM];
            const float4* hv = (const float4*)(h_in + (size_t)u * DIM);
            #pragma unroll
            for (int q = 0; q < 5; ++q) {
                float4 v = hv[q];
                h[q*4] = v.x; h[q*4+1] = v.y; h[q*4+2] = v.z; h[q*4+3] = v.w;
            }
            #pragma unroll
            for (int jj = 0; jj < 5; ++jj) {
                const float* uz = Uz + (size_t)(j0 + jj) * DIM;
                const float* ur = Ur + (size_t)(j0 + jj) * DIM;
                float sz = az[jj], sr = ar[jj];
                #pragma unroll
                for (int k = 0; k < DIM; ++k) {
                    sz += h[k] * uz[k];
                    sr += h[k] * ur[k];
                }
                zz[jj]    = fast_sigmoid(sz);
                rh[jj]    = fast_sigmoid(sr) * h[j0 + jj];
                hmine[jj] = h[j0 + jj];
            }
        }

        // ---- team exchange: rh_all[20] from 4 lanes ----
        float rh_all[DIM];
        int baselane = (tid & 63) & ~3;
        #pragma unroll
        for (int tt = 0; tt < 4; ++tt) {
            #pragma unroll
            for (int i = 0; i < 5; ++i)
                rh_all[tt * 5 + i] = __shfl(rh[i], baselane + tt, 64);
        }

        // ---- phase C: Uh matvec + output ----
        #pragma unroll
        for (int jj = 0; jj < 5; ++jj) {
            const float* uh = Uh + (size_t)(j0 + jj) * DIM;
            float sh = ah[jj];
            #pragma unroll
            for (int k = 0; k < DIM; ++k) sh += rh_all[k] * uh[k];
            float hc = fast_tanh(sh);
            xl[nl * DIM + j0 + jj] = zz[jj] * hmine[jj] + (1.0f - zz[jj]) * hc;
        }
    } else if (isFinal) {
        #pragma unroll
        for (int i = 0; i < 5; ++i) xl[nl * DIM + j0 + i] = 0.0f;
    }
    // note: inactive & !isFinal leaves xl stale -> written to ping-pong h_out,
    // but those rows are never read (gather only touches rows active last iter).
    __syncthreads();

    // ---- epilogue: coalesced stores from LDS ----
    int nb = blockIdx.x * 64;
    for (int i = tid; i < 64 * 5; i += BLOCK) {            // 320 float4
        int node = i / 5, seg = i - node * 5;
        const float* s = xl + node * DIM + seg * 4;
        float4 v = make_float4(s[0], s[1], s[2], s[3]);
        ((float4*)(h_out + (size_t)(nb + node) * DIM))[seg] = v;
    }
    if (!isFinal) {
        for (int i = tid; i < 64 * 10; i += BLOCK) {       // 640 dwords
            int node = i / 10, d = i - node * 10;
            const float* s = xl + node * DIM + d * 2;
            hb_out[(size_t)(nb + node) * 16 + d] = pack_bf16x2(s[0], s[1]);
        }
    }
}

// ---------------- launch ----------------

extern "C" void kernel_launch(void* const* d_in, const int* in_sizes, int n_in,
                              void* d_out, int out_size, void* d_ws, size_t ws_size,
                              hipStream_t stream) {
    const float* h0    = (const float*)d_in[0];
    const int*   depth = (const int*)d_in[1];
    const int*   esrc  = (const int*)d_in[2];
    const int*   edst  = (const int*)d_in[3];
    const float* Wz  = (const float*)d_in[4];  const float* bWz = (const float*)d_in[5];
    const float* Uz  = (const float*)d_in[6];  const float* bUz = (const float*)d_in[7];
    const float* Wr  = (const float*)d_in[8];  const float* bWr = (const float*)d_in[9];
    const float* Ur  = (const float*)d_in[10]; const float* bUr = (const float*)d_in[11];
    const float* Wh  = (const float*)d_in[12]; const float* bWh = (const float*)d_in[13];
    const float* Uh  = (const float*)d_in[14]; const float* bUh = (const float*)d_in[15];
    float* out = (float*)d_out;

    // workspace layout (int32 units)
    int* W = (int*)d_ws;
    int*  fine_cnt      = W + 0;                  // 3125
    int*  fine_base     = W + 3200;               // 3126
    int*  fine_cursor   = W + 6400;               // 3125
    int*  coarse_base   = W + 9600;               // 99
    int*  coarse_cursor = W + 9728;               // 98
    int*  ptr           = W + 9856;               // NN+1
    u32*  cnt3          = (u32*)(W + 209920);     // NN
    u32*  buf1          = (u32*)(W + 409984);     // EE (16B aligned)
    u32*  buf2          = buf1 + EE;              // EE
    float* h1           = (float*)(buf2 + EE);    // NN*DIM
    u32*  hbA           = (u32*)(h1 + (size_t)NN * DIM); // NN*16
    u32*  hbB           = hbA + (size_t)NN * 16;  // NN*16
    float* xbuf         = (float*)(hbB + (size_t)NN * 16); // NN*DIM
    u32*  ssrc          = buf1;                   // alias: buf1 dead after P2
    float* h2           = (float*)buf2;           // alias: buf2 dead after PB

    hipMemsetAsync(fine_cnt, 0, NFINE * sizeof(int), stream);

    int ntile = (EE + TILE - 1) / TILE;           // 1563
    int ggrid = (NN * 4) / BLOCK;                 // 3125 (gather teams)
    int ugrid = NN / 64;                          // 3125 (gru, 64 nodes/block)

    k1_count<<<256, BLOCK, 0, stream>>>(edst, fine_cnt);
    k2_scan <<<1,   BLOCK, 0, stream>>>(fine_cnt, fine_base, fine_cursor,
                                        coarse_base, coarse_cursor);
    p1_split<<<ntile, BLOCK, 0, stream>>>(esrc, edst, depth, coarse_cursor, buf1);
    p2_split<<<ntile, BLOCK, 0, stream>>>(buf1, coarse_base, fine_cursor, buf2);
    pb_sort <<<NFINE, BLOCK, 0, stream>>>(buf2, fine_base, ptr, cnt3, ssrc);
    hconv   <<<(NN * 16) / BLOCK, BLOCK, 0, stream>>>(h0, hbA);

    // iter 0
    gather4  <<<ggrid, BLOCK, 0, stream>>>(hbA, depth, ptr, cnt3, ssrc, xbuf, 0, 20);
    gru_node4<<<ugrid, BLOCK, 0, stream>>>(h0, h1, hbB, depth, xbuf,
        Wz, bWz, Uz, bUz, Wr, bWr, Ur, bUr, Wh, bWh, Uh, bUh, 0, 0);
    // iter 1
    gather4  <<<ggrid, BLOCK, 0, stream>>>(hbB, depth, ptr, cnt3, ssrc, xbuf, 1, 10);
    gru_node4<<<ugrid, BLOCK, 0, stream>>>(h1, h2, hbA, depth, xbuf,
        Wz, bWz, Uz, bUz, Wr, bWr, Ur, bUr, Wh, bWh, Uh, bUh, 1, 0);
    // iter 2
    gather4  <<<ggrid, BLOCK, 0, stream>>>(hbA, depth, ptr, cnt3, ssrc, xbuf, 2, 0);
    gru_node4<<<ugrid, BLOCK, 0, stream>>>(h2, out, hbB, depth, xbuf,
        Wz, bWz, Uz, bUz, Wr, bWr, Ur, bUr, Wh, bWh, Uh, bUh, 2, 1);
}

// Round 7
// 515.742 us; speedup vs baseline: 1.3925x; 1.3925x over previous
//
#include <hip/hip_runtime.h>

#define DIM    20
#define NN     200000
#define EE     6400000
#define ITERS  3
#define BLOCK  256

// Bucketing geometry: fine bucket = 64 nodes
#define NODES_PER_FINE   64
#define NFINE            3125        // 200000/64 exactly
#define NCOARSE          98          // ceil(200000/2048)
#define FINE_PER_COARSE  32
#define TILE             4096        // edges per block tile
#define IPT              16          // items per thread (TILE/BLOCK)
#define XSTRIDE          21          // LDS x stride (gcd(21,32)=1 -> no conflicts)

typedef unsigned int u32;

// ---------------- K1: fine-bucket histogram (LDS-binned) ----------------
__global__ __launch_bounds__(BLOCK) void k1_count(const int* __restrict__ edst,
                                                  int* __restrict__ fine_cnt) {
    __shared__ u32 lhist[NFINE];
    int tid = threadIdx.x;
    for (int i = tid; i < NFINE; i += BLOCK) lhist[i] = 0;
    __syncthreads();
    for (int e = blockIdx.x * BLOCK + tid; e < EE; e += gridDim.x * BLOCK) {
        int d = edst[e];
        atomicAdd(&lhist[d >> 6], 1u);
    }
    __syncthreads();
    for (int i = tid; i < NFINE; i += BLOCK) {
        u32 v = lhist[i];
        if (v) atomicAdd((u32*)&fine_cnt[i], v);
    }
}

// ---------------- K2: scan fine counts -> bases/cursors ----------------
__global__ __launch_bounds__(BLOCK) void k2_scan(const int* __restrict__ fine_cnt,
                                                 int* __restrict__ fine_base,
                                                 int* __restrict__ fine_cursor,
                                                 int* __restrict__ coarse_base,
                                                 int* __restrict__ coarse_cursor) {
    const int CH = 13;                       // 256*13 = 3328 >= 3125
    int tid = threadIdx.x;
    int loc[CH];
    int base = tid * CH;
    int s = 0;
    #pragma unroll
    for (int j = 0; j < CH; ++j) {
        int idx = base + j;
        int v = (idx < NFINE) ? fine_cnt[idx] : 0;
        loc[j] = v; s += v;
    }
    __shared__ int wsum[4];
    int lane = tid & 63, wid = tid >> 6;
    int incl = s;
    #pragma unroll
    for (int off = 1; off < 64; off <<= 1) {
        int t = __shfl_up(incl, off, 64);
        if (lane >= off) incl += t;
    }
    if (lane == 63) wsum[wid] = incl;
    __syncthreads();
    int woff = 0;
    for (int w = 0; w < wid; ++w) woff += wsum[w];
    int run = woff + incl - s;
    #pragma unroll
    for (int j = 0; j < CH; ++j) {
        int idx = base + j;
        if (idx < NFINE) {
            fine_base[idx]   = run;
            fine_cursor[idx] = run;
            run += loc[j];
        }
    }
    if (tid == 0) fine_base[NFINE] = EE;
    __syncthreads();
    if (tid < NCOARSE + 1) {
        int f = tid * FINE_PER_COARSE; if (f > NFINE) f = NFINE;
        int v = fine_base[f];
        coarse_base[tid] = v;
        if (tid < NCOARSE) coarse_cursor[tid] = v;
    }
}

// ---------------- P1: split edges into 98 coarse buckets ----------------
// item u32 = dlow(11) | src<<11 (18) | dep<<29 (3)
__global__ __launch_bounds__(BLOCK) void p1_split(const int* __restrict__ esrc,
                                                  const int* __restrict__ edst,
                                                  const int* __restrict__ depth,
                                                  int* __restrict__ coarse_cursor,
                                                  u32* __restrict__ buf1) {
    __shared__ u32 lhist[NCOARSE];
    __shared__ u32 gbase[NCOARSE];
    int tid = threadIdx.x;
    int start = blockIdx.x * TILE;
    if (tid < NCOARSE) lhist[tid] = 0;
    __syncthreads();

    u32 item[IPT]; u32 key[IPT]; u32 rank[IPT];
    #pragma unroll
    for (int k = 0; k < IPT; ++k) {
        int e = start + k * BLOCK + tid;
        if (e < EE) {
            int d = edst[e];
            int s = esrc[e];
            u32 dep = (u32)depth[s];
            u32 c = (u32)d >> 11;
            key[k]  = c;
            item[k] = ((u32)d & 2047u) | ((u32)s << 11) | (dep << 29);
            rank[k] = atomicAdd(&lhist[c], 1u);
        }
    }
    __syncthreads();
    if (tid < NCOARSE) {
        u32 cnt = lhist[tid];
        gbase[tid] = cnt ? (u32)atomicAdd((u32*)&coarse_cursor[tid], cnt) : 0u;
    }
    __syncthreads();
    #pragma unroll
    for (int k = 0; k < IPT; ++k) {
        int e = start + k * BLOCK + tid;
        if (e < EE) buf1[gbase[key[k]] + rank[k]] = item[k];
    }
}

// ---------------- P2: coarse -> fine (64-node) buckets ----------------
// item u32 = ln(6) | src<<6 (18) | dep<<24 (3)
__global__ __launch_bounds__(BLOCK) void p2_split(const u32* __restrict__ buf1,
                                                  const int* __restrict__ coarse_base,
                                                  int* __restrict__ fine_cursor,
                                                  u32* __restrict__ buf2) {
    __shared__ u32 lhist[2 * FINE_PER_COARSE];
    __shared__ u32 gbase[2 * FINE_PER_COARSE];
    __shared__ int cb[NCOARSE + 1];
    __shared__ int sc0;
    int tid = threadIdx.x;
    int start = blockIdx.x * TILE;
    if (tid < NCOARSE + 1) cb[tid] = coarse_base[tid];
    if (tid < 2 * FINE_PER_COARSE) { lhist[tid] = 0; gbase[tid] = 0; }
    __syncthreads();
    if (tid == 0) {
        int c = 0;
        while (c + 1 < NCOARSE && cb[c + 1] <= start) ++c;
        sc0 = c;
    }
    __syncthreads();
    int c0 = sc0;
    int b1 = cb[c0 + 1];

    u32 item[IPT]; u32 key[IPT]; u32 rank[IPT];
    #pragma unroll
    for (int k = 0; k < IPT; ++k) {
        int i = start + k * BLOCK + tid;
        if (i < EE) {
            u32 w = buf1[i];
            u32 dlow = w & 2047u;
            u32 sdep = w >> 11;               // src(18) | dep<<18
            u32 kk = ((i < b1) ? 0u : (u32)FINE_PER_COARSE) + (dlow >> 6);
            key[k]  = kk;
            item[k] = (dlow & 63u) | (sdep << 6);
            rank[k] = atomicAdd(&lhist[kk], 1u);
        }
    }
    __syncthreads();
    if (tid < 2 * FINE_PER_COARSE) {
        u32 cnt = lhist[tid];
        int idx = c0 * FINE_PER_COARSE + tid;
        if (cnt && idx < NFINE)
            gbase[tid] = (u32)atomicAdd((u32*)&fine_cursor[idx], cnt);
    }
    __syncthreads();
    #pragma unroll
    for (int k = 0; k < IPT; ++k) {
        int i = start + k * BLOCK + tid;
        if (i < EE) buf2[gbase[key[k]] + rank[k]] = item[k];
    }
}

// ---------------- PB: sort each fine bucket by (node, depth) ----------------
// emits node-ordered, depth-sorted ssrc (plain src index) + ptr + packed
// per-depth prefix counts cnt3[u] = c_le1 | c_le2<<10 | c_le3<<20
__global__ __launch_bounds__(BLOCK) void pb_sort(const u32* __restrict__ buf2,
                                                 const int* __restrict__ fine_base,
                                                 int* __restrict__ ptr,
                                                 u32* __restrict__ cnt3,
                                                 u32* __restrict__ ssrc) {
    __shared__ u32 hist[512];
    __shared__ u32 ebase[512];
    __shared__ u32 lout[TILE];
    __shared__ u32 wsum[4];
    int tid = threadIdx.x;
    int b = blockIdx.x;
    int lo = fine_base[b];
    int hi = fine_base[b + 1];
    int cnt = hi - lo;
    hist[tid] = 0; hist[tid + 256] = 0;
    __syncthreads();

    u32 item[IPT]; u32 key[IPT]; u32 rank[IPT];
    #pragma unroll
    for (int k = 0; k < IPT; ++k) {
        int i = lo + k * BLOCK + tid;
        if (i < hi) {
            u32 w = buf2[i];
            u32 kk = (w & 63u) * 8u + (w >> 24);     // ln*8 + dep
            key[k]  = kk;
            item[k] = (w >> 6) & 0x3FFFFu;           // src
            rank[k] = atomicAdd(&hist[kk], 1u);
        }
    }
    __syncthreads();
    {
        u32 s0 = hist[2 * tid], s1 = hist[2 * tid + 1];
        u32 s = s0 + s1;
        int lane = tid & 63, wid = tid >> 6;
        u32 incl = s;
        #pragma unroll
        for (int off = 1; off < 64; off <<= 1) {
            u32 t = __shfl_up((int)incl, off, 64);
            if (lane >= off) incl += t;
        }
        if (lane == 63) wsum[wid] = incl;
        __syncthreads();
        u32 woff = 0;
        for (int w = 0; w < wid; ++w) woff += wsum[w];
        u32 excl = woff + incl - s;
        ebase[2 * tid]     = excl;
        ebase[2 * tid + 1] = excl + s0;
    }
    __syncthreads();
    if (tid < NODES_PER_FINE) {
        u32 base0 = ebase[tid * 8];
        u32 c1 = ebase[tid * 8 + 2] - base0;
        u32 c2 = ebase[tid * 8 + 3] - base0;
        u32 c3 = ebase[tid * 8 + 4] - base0;
        int u = b * NODES_PER_FINE + tid;
        ptr[u]  = lo + (int)base0;
        cnt3[u] = c1 | (c2 << 10) | (c3 << 20);
    }
    #pragma unroll
    for (int k = 0; k < IPT; ++k) {
        int i = lo + k * BLOCK + tid;
        if (i < hi) lout[ebase[key[k]] + rank[k]] = item[k];
    }
    __syncthreads();
    for (int j = tid; j < cnt; j += BLOCK) ssrc[lo + j] = lout[j];
}

// ---------------- hconv: fp32 h -> bf16 rows padded to 64 B ----------------
__device__ __forceinline__ u32 pack_bf16x2(float a, float b) {
    u32 ua = __float_as_uint(a);
    u32 ub = __float_as_uint(b);
    ua = (ua + 0x7FFFu + ((ua >> 16) & 1u)) >> 16;
    ub = (ub + 0x7FFFu + ((ub >> 16) & 1u)) & 0xFFFF0000u;
    return ua | ub;
}

__global__ __launch_bounds__(BLOCK) void hconv(const float* __restrict__ h,
                                               u32* __restrict__ hb) {
    int g = blockIdx.x * BLOCK + threadIdx.x;
    if (g >= NN * 16) return;
    int node = g >> 4, slot = g & 15;
    u32 v = 0;
    if (slot < 10) {
        float2 f = *(const float2*)(h + (size_t)node * DIM + slot * 2);
        v = pack_bf16x2(f.x, f.y);
    }
    hb[g] = v;
}

// ---------------- fused iteration: gather (all waves) + GRU (wave 0) ----------------

__device__ __forceinline__ float bl(u32 w) { return __uint_as_float(w << 16); }
__device__ __forceinline__ float bh(u32 w) { return __uint_as_float(w & 0xFFFF0000u); }

__device__ __forceinline__ void acc_bf16row(float* x, uint4 A, uint4 B, uint2 C) {
    x[0]+=bl(A.x);  x[1]+=bh(A.x);  x[2]+=bl(A.y);  x[3]+=bh(A.y);
    x[4]+=bl(A.z);  x[5]+=bh(A.z);  x[6]+=bl(A.w);  x[7]+=bh(A.w);
    x[8]+=bl(B.x);  x[9]+=bh(B.x);  x[10]+=bl(B.y); x[11]+=bh(B.y);
    x[12]+=bl(B.z); x[13]+=bh(B.z); x[14]+=bl(B.w); x[15]+=bh(B.w);
    x[16]+=bl(C.x); x[17]+=bh(C.x); x[18]+=bl(C.y); x[19]+=bh(C.y);
}

__device__ __forceinline__ float fast_sigmoid(float t) {
    return 1.0f / (1.0f + __expf(-t));
}
__device__ __forceinline__ float fast_tanh(float t) {
    t = fminf(fmaxf(t, -15.0f), 15.0f);
    float e2 = __expf(2.0f * t);
    return (e2 - 1.0f) / (e2 + 1.0f);
}

__global__ __launch_bounds__(BLOCK) void grnn_iter(
    const float* __restrict__ h_in, float* __restrict__ h_out,
    const u32* __restrict__ hb_in, u32* __restrict__ hb_out,
    const int* __restrict__ depth, const int* __restrict__ ptr,
    const u32* __restrict__ cnt3, const u32* __restrict__ ssrc,
    const float* __restrict__ Wz, const float* __restrict__ bWz,
    const float* __restrict__ Uz, const float* __restrict__ bUz,
    const float* __restrict__ Wr, const float* __restrict__ bWr,
    const float* __restrict__ Ur, const float* __restrict__ bUr,
    const float* __restrict__ Wh, const float* __restrict__ bWh,
    const float* __restrict__ Uh, const float* __restrict__ bUh,
    int it, int shift, int isFinal)
{
    __shared__ float xl[64 * XSTRIDE];     // 5376 B
    int tid = threadIdx.x;
    int nl  = tid >> 2;                    // node within block
    int t   = tid & 3;                     // team lane
    int lim = ITERS - it;

    // ---- phase 1: edge gather, 4-lane teams, register accumulate ----
    {
        int u = blockIdx.x * 64 + nl;
        if (depth[u] <= lim) {
            int p = ptr[u];
            int d = (int)((cnt3[u] >> shift) & 1023u);
            float x[DIM];
            #pragma unroll
            for (int k = 0; k < DIM; ++k) x[k] = 0.0f;
            int e = t;
            for (; e + 4 < d; e += 8) {
                u32 v0 = ssrc[p + e];
                u32 v1 = ssrc[p + e + 4];
                const u32* r0 = hb_in + (size_t)v0 * 16;
                const u32* r1 = hb_in + (size_t)v1 * 16;
                uint4 A0 = *(const uint4*)r0; uint4 B0 = *(const uint4*)(r0 + 4);
                uint2 C0 = *(const uint2*)(r0 + 8);
                uint4 A1 = *(const uint4*)r1; uint4 B1 = *(const uint4*)(r1 + 4);
                uint2 C1 = *(const uint2*)(r1 + 8);
                acc_bf16row(x, A0, B0, C0);
                acc_bf16row(x, A1, B1, C1);
            }
            if (e < d) {
                u32 v0 = ssrc[p + e];
                const u32* r0 = hb_in + (size_t)v0 * 16;
                uint4 A0 = *(const uint4*)r0; uint4 B0 = *(const uint4*)(r0 + 4);
                uint2 C0 = *(const uint2*)(r0 + 8);
                acc_bf16row(x, A0, B0, C0);
            }
            #pragma unroll
            for (int k = 0; k < DIM; ++k) {
                x[k] += __shfl_xor(x[k], 1, 64);
                x[k] += __shfl_xor(x[k], 2, 64);
            }
            float* xr = xl + nl * XSTRIDE;
            #pragma unroll
            for (int q = 0; q < 5; ++q) xr[q * 4 + t] = x[q * 4 + t];
        }
    }
    __syncthreads();
    if (tid >= 64) return;                 // waves 1-3 retire

    // ---- phase 2: GRU, thread-per-node, wave-uniform scalar weights ----
    int u = blockIdx.x * 64 + tid;
    bool act = depth[u] <= lim;
    if (!act) {
        if (isFinal) {
            float4 z4 = make_float4(0.f, 0.f, 0.f, 0.f);
            float4* o4 = (float4*)(h_out + (size_t)u * DIM);
            #pragma unroll
            for (int q = 0; q < 5; ++q) o4[q] = z4;
        }
        return;
    }

    float x[DIM], h[DIM];
    #pragma unroll
    for (int k = 0; k < DIM; ++k) x[k] = xl[tid * XSTRIDE + k];
    {
        const float4* hv = (const float4*)(h_in + (size_t)u * DIM);
        float4 a0 = hv[0], a1 = hv[1], a2 = hv[2], a3 = hv[3], a4 = hv[4];
        h[0]=a0.x; h[1]=a0.y; h[2]=a0.z; h[3]=a0.w;
        h[4]=a1.x; h[5]=a1.y; h[6]=a1.z; h[7]=a1.w;
        h[8]=a2.x; h[9]=a2.y; h[10]=a2.z; h[11]=a2.w;
        h[12]=a3.x; h[13]=a3.y; h[14]=a3.z; h[15]=a3.w;
        h[16]=a4.x; h[17]=a4.y; h[18]=a4.z; h[19]=a4.w;
    }

    float z[DIM], rh[DIM];
    #pragma unroll
    for (int j = 0; j < DIM; ++j) {
        float sz = bWz[j] + bUz[j];
        float sr = bWr[j] + bUr[j];
        #pragma unroll
        for (int k = 0; k < DIM; ++k) {
            sz += x[k] * Wz[j * DIM + k];
            sz += h[k] * Uz[j * DIM + k];
            sr += x[k] * Wr[j * DIM + k];
            sr += h[k] * Ur[j * DIM + k];
        }
        z[j]  = fast_sigmoid(sz);
        rh[j] = fast_sigmoid(sr) * h[j];
    }

    float o[DIM];
    #pragma unroll
    for (int j = 0; j < DIM; ++j) {
        float sh = bWh[j] + bUh[j];
        #pragma unroll
        for (int k = 0; k < DIM; ++k) {
            sh += x[k]  * Wh[j * DIM + k];
            sh += rh[k] * Uh[j * DIM + k];
        }
        float hc = fast_tanh(sh);
        o[j] = z[j] * h[j] + (1.0f - z[j]) * hc;
    }

    {
        float4* o4 = (float4*)(h_out + (size_t)u * DIM);
        o4[0] = make_float4(o[0],  o[1],  o[2],  o[3]);
        o4[1] = make_float4(o[4],  o[5],  o[6],  o[7]);
        o4[2] = make_float4(o[8],  o[9],  o[10], o[11]);
        o4[3] = make_float4(o[12], o[13], o[14], o[15]);
        o4[4] = make_float4(o[16], o[17], o[18], o[19]);
    }
    if (!isFinal) {
        u32* row = hb_out + (size_t)u * 16;
        uint4 wA = make_uint4(pack_bf16x2(o[0], o[1]),  pack_bf16x2(o[2], o[3]),
                              pack_bf16x2(o[4], o[5]),  pack_bf16x2(o[6], o[7]));
        uint4 wB = make_uint4(pack_bf16x2(o[8], o[9]),  pack_bf16x2(o[10], o[11]),
                              pack_bf16x2(o[12], o[13]), pack_bf16x2(o[14], o[15]));
        uint2 wC = make_uint2(pack_bf16x2(o[16], o[17]), pack_bf16x2(o[18], o[19]));
        *(uint4*)row       = wA;
        *(uint4*)(row + 4) = wB;
        *(uint2*)(row + 8) = wC;
    }
}

// ---------------- launch ----------------

extern "C" void kernel_launch(void* const* d_in, const int* in_sizes, int n_in,
                              void* d_out, int out_size, void* d_ws, size_t ws_size,
                              hipStream_t stream) {
    const float* h0    = (const float*)d_in[0];
    const int*   depth = (const int*)d_in[1];
    const int*   esrc  = (const int*)d_in[2];
    const int*   edst  = (const int*)d_in[3];
    const float* Wz  = (const float*)d_in[4];  const float* bWz = (const float*)d_in[5];
    const float* Uz  = (const float*)d_in[6];  const float* bUz = (const float*)d_in[7];
    const float* Wr  = (const float*)d_in[8];  const float* bWr = (const float*)d_in[9];
    const float* Ur  = (const float*)d_in[10]; const float* bUr = (const float*)d_in[11];
    const float* Wh  = (const float*)d_in[12]; const float* bWh = (const float*)d_in[13];
    const float* Uh  = (const float*)d_in[14]; const float* bUh = (const float*)d_in[15];
    float* out = (float*)d_out;

    // workspace layout (int32 units)
    int* W = (int*)d_ws;
    int*  fine_cnt      = W + 0;                  // 3125
    int*  fine_base     = W + 3200;               // 3126
    int*  fine_cursor   = W + 6400;               // 3125
    int*  coarse_base   = W + 9600;               // 99
    int*  coarse_cursor = W + 9728;               // 98
    int*  ptr           = W + 9856;               // NN+1
    u32*  cnt3          = (u32*)(W + 209920);     // NN
    u32*  buf1          = (u32*)(W + 409984);     // EE (16B aligned)
    u32*  buf2          = buf1 + EE;              // EE
    float* h1           = (float*)(buf2 + EE);    // NN*DIM
    u32*  hbA           = (u32*)(h1 + (size_t)NN * DIM); // NN*16
    u32*  hbB           = hbA + (size_t)NN * 16;  // NN*16
    u32*  ssrc          = buf1;                   // alias: buf1 dead after P2
    float* h2           = (float*)buf2;           // alias: buf2 dead after PB

    hipMemsetAsync(fine_cnt, 0, NFINE * sizeof(int), stream);

    int ntile = (EE + TILE - 1) / TILE;           // 1563

    k1_count<<<256, BLOCK, 0, stream>>>(edst, fine_cnt);
    k2_scan <<<1,   BLOCK, 0, stream>>>(fine_cnt, fine_base, fine_cursor,
                                        coarse_base, coarse_cursor);
    p1_split<<<ntile, BLOCK, 0, stream>>>(esrc, edst, depth, coarse_cursor, buf1);
    p2_split<<<ntile, BLOCK, 0, stream>>>(buf1, coarse_base, fine_cursor, buf2);
    pb_sort <<<NFINE, BLOCK, 0, stream>>>(buf2, fine_base, ptr, cnt3, ssrc);
    hconv   <<<(NN * 16) / BLOCK, BLOCK, 0, stream>>>(h0, hbA);

    grnn_iter<<<NFINE, BLOCK, 0, stream>>>(h0, h1, hbA, hbB, depth, ptr, cnt3, ssrc,
        Wz, bWz, Uz, bUz, Wr, bWr, Ur, bUr, Wh, bWh, Uh, bUh, 0, 20, 0);
    grnn_iter<<<NFINE, BLOCK, 0, stream>>>(h1, h2, hbB, hbA, depth, ptr, cnt3, ssrc,
        Wz, bWz, Uz, bUz, Wr, bWr, Ur, bUr, Wh, bWh, Uh, bUh, 1, 10, 0);
    grnn_iter<<<NFINE, BLOCK, 0, stream>>>(h2, out, hbA, hbB, depth, ptr, cnt3, ssrc,
        Wz, bWz, Uz, bUz, Wr, bWr, Ur, bUr, Wh, bWh, Uh, bUh, 2, 0, 1);
}